// Round 10
// baseline (208.511 us; speedup 1.0000x reference)
//
#include <hip/hip_runtime.h>
#include <hip/hip_bf16.h>

#define F_OUT 64
#define NEG_SLOPE 0.2f
#define SOFT_EPS 1e-16f
#define BW 256          // nodes per bucket (i_local fits in 8 bits)
#define CH 8192         // edges per chunk
#define TH 512          // threads for count/scatter blocks
#define TH3 512         // threads for bucket_csr

typedef short short8 __attribute__((ext_vector_type(8)));
typedef float floatx4 __attribute__((ext_vector_type(4)));
typedef unsigned short ushort8v __attribute__((ext_vector_type(8)));
typedef unsigned short ushort4v __attribute__((ext_vector_type(4)));
typedef long long ll2 __attribute__((ext_vector_type(2)));
typedef int int2v __attribute__((ext_vector_type(2)));

__device__ __forceinline__ unsigned short f2bf_bits(float v) {
    __hip_bfloat16 hb = __float2bfloat16(v);
    return *(unsigned short*)&hb;
}
__device__ __forceinline__ float bf_bits2f(unsigned short u) {
    __hip_bfloat16 hb = *(__hip_bfloat16*)&u;
    return __bfloat162float(hb);
}
__device__ __forceinline__ float read_any(const void* src, int off, int bf) {
    return bf ? __bfloat162float(((const __hip_bfloat16*)src)[off])
              : ((const float*)src)[off];
}
__device__ __forceinline__ int get_idx(const void* ei, int i64, long long pos) {
    return i64 ? (int)((const long long*)ei)[pos] : ((const int*)ei)[pos];
}

// Per-block dtype detection (64-lane ballot on W1 low-halves / ei high words).
__device__ __forceinline__ void detect_local(const unsigned* wbits, const unsigned* ebits,
                                             int* sm_bf, int* sm_i64) {
    if (threadIdx.x < 64) {
        unsigned w = wbits[threadIdx.x];
        unsigned e = (w >> 7) & 0xFFu;
        unsigned long long mb = __ballot(e >= 0x60u && e <= 0x7Eu);
        unsigned long long mz = __ballot(ebits[2 * threadIdx.x + 1] == 0u);
        if (threadIdx.x == 0) { *sm_bf = (__popcll(mb) > 32); *sm_i64 = (__popcll(mz) > 32); }
    }
    __syncthreads();
}

// Load a pair of indices (stream base + t, t+1) vectorized.
__device__ __forceinline__ void load_idx2(const void* ei, int i64, long long base, int t,
                                          int* v0, int* v1) {
    if (i64) {
        ll2 d = *(const ll2*)((const long long*)ei + base + t);
        *v0 = (int)d[0]; *v1 = (int)d[1];
    } else {
        int2v d = *(const int2v*)((const int*)ei + base + t);
        *v0 = d[0]; *v1 = d[1];
    }
}

// ---------- D1: bucket_count (blocks 0..nchunks-1) ∥ prep weights (block nchunks) ----------
__global__ void count_prep(const void* __restrict__ ei, int* __restrict__ table,
                           const void* w1, const void* as1, const void* ad1, const void* b1,
                           const void* w2, const void* as2, const void* ad2, const void* b2,
                           unsigned short* __restrict__ wt1, unsigned short* __restrict__ wt2,
                           float* __restrict__ vecs, int* __restrict__ flags,
                           int E, int total, int NB, int nchunks, int n1, int n2, int K1) {
    __shared__ int cnt[1024];
    __shared__ int s_bf, s_i64;
    detect_local((const unsigned*)w1, (const unsigned*)ei, &s_bf, &s_i64);
    int bf = s_bf, i64 = s_i64;
    int g = blockIdx.x, tid = threadIdx.x;
    if (g == 0 && tid == 0) { flags[0] = bf; flags[1] = i64; }

    if (g < nchunks) {                     // ---- counting block ----
        for (int k = tid; k < NB; k += TH) cnt[k] = 0;
        __syncthreads();
        int base = g * CH;
        int lim = base + CH < total ? base + CH : total;
        int elim = lim < E ? lim : E;      // edge sub-range end
        for (int t = base + tid * 2; t < elim; t += TH * 2) {
            if (t + 1 < elim) {
                int i0, i1;
                load_idx2(ei, i64, (long long)E, t, &i0, &i1);
                atomicAdd(&cnt[i0 >> 8], 1);
                atomicAdd(&cnt[i1 >> 8], 1);
            } else {
                int i0 = get_idx(ei, i64, (long long)E + t);
                atomicAdd(&cnt[i0 >> 8], 1);
            }
        }
        for (int t = (base > E ? base : E) + tid; t < lim; t += TH)
            atomicAdd(&cnt[(t - E) >> 8], 1);
        __syncthreads();
        for (int k = tid; k < NB; k += TH) table[k * nchunks + g] = cnt[k];
    } else {                               // ---- weight-prep block ----
        int wtotal = n1 + n2 + 384;
        for (int t = tid; t < wtotal; t += TH) {
            if (t < n1) {
                int n = t / K1, k = t - n * K1;
                wt1[t] = f2bf_bits(read_any(w1, k * F_OUT + n, bf));
            } else if (t < n1 + n2) {
                int u = t - n1;
                int n = u >> 6, k = u & 63;
                wt2[u] = f2bf_bits(read_any(w2, k * F_OUT + n, bf));
            } else {
                int u = t - n1 - n2;
                const void* srcp[6] = {as1, ad1, b1, as2, ad2, b2};
                vecs[u] = read_any(srcp[u >> 6], u & 63, bf);
            }
        }
    }
}

// ---------- MFMA GEMM body (WAVES waves x 16 rows per block, global bf16/f32 A) ----------
template <int K, int WAVES>
__device__ __forceinline__ void gemm_body(int blk, int tid,
                          const void* __restrict__ xv, const unsigned short* __restrict__ Wt,
                          const float* __restrict__ att_s, const float* __restrict__ att_d,
                          unsigned short* __restrict__ h, float* __restrict__ a_s,
                          float* __restrict__ a_d, int N, int bf) {
    int lane = tid & 63;
    int m0 = (blk * WAVES + (tid >> 6)) * 16;
    if (m0 >= N) return;
    int c = lane & 15, quad = lane >> 4;
    int arow = m0 + c;
    if (arow >= N) arow = N - 1;

    floatx4 acc0 = {0.f, 0.f, 0.f, 0.f};
    floatx4 acc1 = acc0, acc2 = acc0, acc3 = acc0;

    for (int kc = 0; kc < K; kc += 32) {
        int ka = kc + quad * 8;
        short8 a;
        if (bf) {
            a = *(const short8*)((const unsigned short*)xv + (size_t)arow * K + ka);
        } else {
            const float* xp = (const float*)xv + (size_t)arow * K + ka;
            floatx4 f0 = *(const floatx4*)xp;
            floatx4 f1 = *(const floatx4*)(xp + 4);
#pragma unroll
            for (int j = 0; j < 4; ++j) {
                a[j]     = (short)f2bf_bits(f0[j]);
                a[4 + j] = (short)f2bf_bits(f1[j]);
            }
        }
        short8 b0 = *(const short8*)(Wt + (size_t)(c)      * K + ka);
        short8 b1 = *(const short8*)(Wt + (size_t)(16 + c) * K + ka);
        short8 b2 = *(const short8*)(Wt + (size_t)(32 + c) * K + ka);
        short8 b3 = *(const short8*)(Wt + (size_t)(48 + c) * K + ka);
        acc0 = __builtin_amdgcn_mfma_f32_16x16x32_bf16(a, b0, acc0, 0, 0, 0);
        acc1 = __builtin_amdgcn_mfma_f32_16x16x32_bf16(a, b1, acc1, 0, 0, 0);
        acc2 = __builtin_amdgcn_mfma_f32_16x16x32_bf16(a, b2, acc2, 0, 0, 0);
        acc3 = __builtin_amdgcn_mfma_f32_16x16x32_bf16(a, b3, acc3, 0, 0, 0);
    }

    float as0 = att_s[c],      as1 = att_s[16 + c], as2 = att_s[32 + c], as3 = att_s[48 + c];
    float ad0 = att_d[c],      ad1 = att_d[16 + c], ad2 = att_d[32 + c], ad3 = att_d[48 + c];
#pragma unroll
    for (int reg = 0; reg < 4; ++reg) {
        int row = m0 + quad * 4 + reg;
        float vs = acc0[reg] * as0 + acc1[reg] * as1 + acc2[reg] * as2 + acc3[reg] * as3;
        float vd = acc0[reg] * ad0 + acc1[reg] * ad1 + acc2[reg] * ad2 + acc3[reg] * ad3;
#pragma unroll
        for (int off = 1; off < 16; off <<= 1) {
            vs += __shfl_xor(vs, off);
            vd += __shfl_xor(vd, off);
        }
        if (row < N) {
            if (c == 0) { a_s[row] = vs; a_d[row] = vd; }
            unsigned short* hr = h + (size_t)row * F_OUT + c;
            hr[0]  = f2bf_bits(acc0[reg]);
            hr[16] = f2bf_bits(acc1[reg]);
            hr[32] = f2bf_bits(acc2[reg]);
            hr[48] = f2bf_bits(acc3[reg]);
        }
    }
}

// ---------- D2: scatter (blocks < nchunks, cursors self-computed from raw table)
//              ∥ layer-1 GEMM (remaining blocks, 8 waves x 16 rows) ----------
__global__ void __launch_bounds__(TH)
scatter_gemm1(const void* __restrict__ ei, const int* __restrict__ table,
              unsigned* __restrict__ staged, int* __restrict__ segbeg,
              int* __restrict__ row_ptr, const void* __restrict__ xv,
              const unsigned short* __restrict__ Wt,
              const float* __restrict__ att_s, const float* __restrict__ att_d,
              unsigned short* __restrict__ h, float* __restrict__ a_s,
              float* __restrict__ a_d, const unsigned* __restrict__ wbits,
              int E, int total, int NB, int nchunks, int N) {
    __shared__ int s_bf, s_i64;
    detect_local(wbits, (const unsigned*)ei, &s_bf, &s_i64);
    int tid = threadIdx.x;
    if ((int)blockIdx.x >= nchunks) {      // ---- layer-1 GEMM role ----
        gemm_body<128, 8>(blockIdx.x - nchunks, tid, xv, Wt, att_s, att_d,
                          h, a_s, a_d, N, s_bf);
        return;
    }
    // ---- scatter role ----
    __shared__ int s_scan[TH];
    __shared__ int s_cur[1024];
    int g = blockIdx.x;
    int i64 = s_i64;
    int b0 = 0;
    if (tid < NB) {                        // NB (=196) <= TH
        const int* row = table + (size_t)tid * nchunks;
        int rsum = 0, rpart = 0;
        for (int c2 = 0; c2 < nchunks; ++c2) {
            int v = row[c2];
            rsum += v;
            rpart += (c2 < g) ? v : 0;
        }
        b0 = rsum;
        s_cur[tid] = rpart;
    }
    s_scan[tid] = (tid < NB) ? b0 : 0;
    __syncthreads();
    for (int off = 1; off < TH; off <<= 1) {   // Hillis-Steele inclusive scan
        int v = (tid >= off) ? s_scan[tid - off] : 0;
        __syncthreads();
        s_scan[tid] += v;
        __syncthreads();
    }
    if (tid < NB) {
        int excl = s_scan[tid] - b0;
        s_cur[tid] = excl + s_cur[tid];
        if (g == 0) segbeg[tid] = excl;
    }
    if (g == 0 && tid == 0) { segbeg[NB] = total; row_ptr[N] = total; }
    __syncthreads();
    int base = g * CH;
    int lim = base + CH < total ? base + CH : total;
    int elim = lim < E ? lim : E;          // edge sub-range end
    for (int t = base + tid * 2; t < elim; t += TH * 2) {
        if (t + 1 < elim) {
            int j0, j1, i0, i1;
            load_idx2(ei, i64, 0, t, &j0, &j1);
            load_idx2(ei, i64, (long long)E, t, &i0, &i1);
            int pos0 = atomicAdd(&s_cur[i0 >> 8], 1);
            staged[pos0] = ((unsigned)(i0 & 255) << 24) | (unsigned)j0;
            int pos1 = atomicAdd(&s_cur[i1 >> 8], 1);
            staged[pos1] = ((unsigned)(i1 & 255) << 24) | (unsigned)j1;
        } else {
            int j0 = get_idx(ei, i64, t);
            int i0 = get_idx(ei, i64, (long long)E + t);
            int pos0 = atomicAdd(&s_cur[i0 >> 8], 1);
            staged[pos0] = ((unsigned)(i0 & 255) << 24) | (unsigned)j0;
        }
    }
    for (int t = (base > E ? base : E) + tid; t < lim; t += TH) {
        int v = t - E;
        int pos = atomicAdd(&s_cur[v >> 8], 1);
        staged[pos] = ((unsigned)(v & 255) << 24) | (unsigned)v;
    }
}

// ---------- D3: per-bucket CSR (row_ptr + in-segment eidx) ----------
__global__ void __launch_bounds__(TH3)
bucket_csr(const unsigned* __restrict__ staged, const int* __restrict__ segbeg,
           int* __restrict__ row_ptr, int* __restrict__ eidx, int N) {
    __shared__ int ldeg[BW];
    __shared__ int lcur[BW];
    __shared__ int wtot[4];
    int b = blockIdx.x;
    int t = threadIdx.x;
    int seg_beg = segbeg[b];
    int seg_end = segbeg[b + 1];
    if (t < BW) ldeg[t] = 0;
    __syncthreads();
    for (int p = seg_beg + t; p < seg_end; p += TH3)
        atomicAdd(&ldeg[staged[p] >> 24], 1);
    __syncthreads();
    int lane = t & 63, w = t >> 6;
    int d = 0, v = 0;
    if (t < BW) {
        d = ldeg[t];
        v = d;
#pragma unroll
        for (int off = 1; off < 64; off <<= 1) {
            int u = __shfl_up(v, off);
            if (lane >= off) v += u;
        }
        if (lane == 63) wtot[w] = v;
    }
    __syncthreads();
    if (t < BW) {
        int woff = 0;
        for (int k = 0; k < w; ++k) woff += wtot[k];
        int excl = v - d + woff;
        int node = b * BW + t;
        if (node < N) row_ptr[node] = seg_beg + excl;
        lcur[t] = excl;
    }
    __syncthreads();
    for (int p = seg_beg + t; p < seg_end; p += TH3) {
        unsigned pk = staged[p];
        int pos = atomicAdd(&lcur[pk >> 24], 1);
        eidx[seg_beg + pos] = (int)(pk & 0xFFFFFFu);
    }
}

// ---------- dual-node HALF-ROW gather wave body ----------
// Same stream structure as the R8 dual-node body, but each phase touches only
// one 64B half of every h row (phase*64 + c8*8 bytes): the chip-wide working
// set per phase is 3.2MB -> fits each XCD's 4MiB L2, turning the random row
// reads from ~600cy L3 hits into ~200cy L2 hits. se is recomputed identically
// in each phase (same edges, same order -> bit-identical).
__device__ __forceinline__ void gather_half8x2(int ia, int ib, int grp, int c8, int phase,
                                               const int* __restrict__ row_ptr,
                                               const int* __restrict__ eidx,
                                               const float* __restrict__ a_s,
                                               const float* __restrict__ a_d,
                                               const unsigned short* __restrict__ h,
                                               float* sea_out, float acca[4],
                                               float* seb_out, float accb[4], int N) {
    const char* hb8 = (const char*)h;
    unsigned cofs = ((unsigned)phase << 6) + ((unsigned)c8 << 3);
    int bega = row_ptr[ia], enda = row_ptr[ia + 1];
    int lena = enda - bega;
    float ada = a_d[ia];
    int pa = bega + ((lena * grp) >> 3);
    int gea = bega + ((lena * (grp + 1)) >> 3);
    int pb = 0, geb = 0;
    float adb = 0.f;
    if (ib < N) {
        int begb = row_ptr[ib], endb = row_ptr[ib + 1];
        int lenb = endb - begb;
        adb = a_d[ib];
        pb = begb + ((lenb * grp) >> 3);
        geb = begb + ((lenb * (grp + 1)) >> 3);
    }
    float sea = 0.f, seb = 0.f;
#pragma unroll
    for (int k = 0; k < 4; ++k) { acca[k] = 0.f; accb[k] = 0.f; }

    while (pa < gea || pb < geb) {
        bool va0 = pa < gea, va1 = pa + 1 < gea;
        bool vb0 = pb < geb, vb1 = pb + 1 < geb;
        int ja0 = va0 ? eidx[pa]     : 0;
        int ja1 = va1 ? eidx[pa + 1] : 0;
        int jb0 = vb0 ? eidx[pb]     : 0;
        int jb1 = vb1 ? eidx[pb + 1] : 0;
        ushort4v ha0 = *(const ushort4v*)(hb8 + (((unsigned)ja0 << 7) + cofs));
        ushort4v ha1 = *(const ushort4v*)(hb8 + (((unsigned)ja1 << 7) + cofs));
        ushort4v hb0 = *(const ushort4v*)(hb8 + (((unsigned)jb0 << 7) + cofs));
        ushort4v hb1 = *(const ushort4v*)(hb8 + (((unsigned)jb1 << 7) + cofs));
        float ea0 = a_s[ja0] + ada;
        float ea1 = a_s[ja1] + ada;
        float eb0 = a_s[jb0] + adb;
        float eb1 = a_s[jb1] + adb;
        float wa0 = va0 ? __expf(fmaxf(ea0, NEG_SLOPE * ea0)) : 0.f;
        float wa1 = va1 ? __expf(fmaxf(ea1, NEG_SLOPE * ea1)) : 0.f;
        float wb0 = vb0 ? __expf(fmaxf(eb0, NEG_SLOPE * eb0)) : 0.f;
        float wb1 = vb1 ? __expf(fmaxf(eb1, NEG_SLOPE * eb1)) : 0.f;
        sea += wa0 + wa1;
        seb += wb0 + wb1;
#pragma unroll
        for (int k = 0; k < 4; ++k) {
            acca[k] += wa0 * bf_bits2f(ha0[k]) + wa1 * bf_bits2f(ha1[k]);
            accb[k] += wb0 * bf_bits2f(hb0[k]) + wb1 * bf_bits2f(hb1[k]);
        }
        pa += 2; pb += 2;
    }

    // cross-group reduce: 3 levels, every lane ends with full sums
#pragma unroll
    for (int off = 8; off < 64; off <<= 1) {
        sea += __shfl_xor(sea, off);
        seb += __shfl_xor(seb, off);
#pragma unroll
        for (int k = 0; k < 4; ++k) {
            acca[k] += __shfl_xor(acca[k], off);
            accb[k] += __shfl_xor(accb[k], off);
        }
    }
    *sea_out = sea;
    *seb_out = seb;
}

// ---------- D4a: layer-1 gather phase 0 (cols 0..31) -> x1lo staging ----------
__global__ void __launch_bounds__(256)
gather1_p0(const int* __restrict__ row_ptr, const int* __restrict__ eidx,
           const float* __restrict__ a_s, const float* __restrict__ a_d,
           const unsigned short* __restrict__ h, const float* __restrict__ bias,
           unsigned short* __restrict__ x1lo, int N) {
    int lane = threadIdx.x & 63;
    int wv = threadIdx.x >> 6;            // 0..3
    int ia = blockIdx.x * 8 + (wv << 1);
    int ib = ia + 1;
    if (ia >= N) return;
    int grp = lane >> 3, c8 = lane & 7;
    float sea, seb, acca[4], accb[4];
    gather_half8x2(ia, ib, grp, c8, 0, row_ptr, eidx, a_s, a_d, h,
                   &sea, acca, &seb, accb, N);
    if (grp == 0) {
        int col = c8 << 2;
        float inv = 1.f / (sea + SOFT_EPS);
        ushort4v ov;
#pragma unroll
        for (int k = 0; k < 4; ++k) {
            float v = acca[k] * inv + bias[col + k];
            ov[k] = f2bf_bits(v > 0.f ? v : 0.f);
        }
        *(ushort4v*)(x1lo + (size_t)ia * 32 + col) = ov;
        if (ib < N) {
            inv = 1.f / (seb + SOFT_EPS);
#pragma unroll
            for (int k = 0; k < 4; ++k) {
                float v = accb[k] * inv + bias[col + k];
                ov[k] = f2bf_bits(v > 0.f ? v : 0.f);
            }
            *(ushort4v*)(x1lo + (size_t)ib * 32 + col) = ov;
        }
    }
}

// ---------- D4b: layer-1 gather phase 1 (cols 32..63) + layer-2 GEMM ----------
#define XST 72
__global__ void __launch_bounds__(512)
gather1_p1(const int* __restrict__ row_ptr, const int* __restrict__ eidx,
           const float* __restrict__ a_s, const float* __restrict__ a_d,
           const unsigned short* __restrict__ h, const float* __restrict__ bias,
           const unsigned short* __restrict__ x1lo,
           const unsigned short* __restrict__ Wt2,
           const float* __restrict__ att_s2, const float* __restrict__ att_d2,
           unsigned short* __restrict__ h2, float* __restrict__ a_s2,
           float* __restrict__ a_d2, int N) {
    __shared__ unsigned short x1t[16 * XST];
    int tid = threadIdx.x;
    int lane = tid & 63;
    int wv = tid >> 6;                    // 0..7 -> rows 2wv, 2wv+1
    int grp = lane >> 3, c8 = lane & 7;
    int ia = blockIdx.x * 16 + (wv << 1);
    int ib = ia + 1;

    if (ia < N) {
        float sea, seb, acca[4], accb[4];
        gather_half8x2(ia, ib, grp, c8, 1, row_ptr, eidx, a_s, a_d, h,
                       &sea, acca, &seb, accb, N);
        if (grp == 0) {
            int col = c8 << 2;
            // lower half from staging, upper half from this phase's acc
            ushort4v lo = *(const ushort4v*)(x1lo + (size_t)ia * 32 + col);
            *(ushort4v*)(x1t + (wv * 2) * XST + col) = lo;
            float inv = 1.f / (sea + SOFT_EPS);
            ushort4v ov;
#pragma unroll
            for (int k = 0; k < 4; ++k) {
                float v = acca[k] * inv + bias[32 + col + k];
                ov[k] = f2bf_bits(v > 0.f ? v : 0.f);
            }
            *(ushort4v*)(x1t + (wv * 2) * XST + 32 + col) = ov;
            if (ib < N) {
                lo = *(const ushort4v*)(x1lo + (size_t)ib * 32 + col);
                inv = 1.f / (seb + SOFT_EPS);
#pragma unroll
                for (int k = 0; k < 4; ++k) {
                    float v = accb[k] * inv + bias[32 + col + k];
                    ov[k] = f2bf_bits(v > 0.f ? v : 0.f);
                }
            } else {
                lo = (ushort4v){0, 0, 0, 0};
                ov = (ushort4v){0, 0, 0, 0};
            }
            *(ushort4v*)(x1t + (wv * 2 + 1) * XST + col) = lo;
            *(ushort4v*)(x1t + (wv * 2 + 1) * XST + 32 + col) = ov;
        }
    } else if (grp == 0) {
        ushort4v z = (ushort4v){0, 0, 0, 0};
        int col = c8 << 2;
        *(ushort4v*)(x1t + (wv * 2)     * XST + col) = z;
        *(ushort4v*)(x1t + (wv * 2)     * XST + 32 + col) = z;
        *(ushort4v*)(x1t + (wv * 2 + 1) * XST + col) = z;
        *(ushort4v*)(x1t + (wv * 2 + 1) * XST + 32 + col) = z;
    }
    __syncthreads();

    if (wv == 0) {                        // ---- layer-2 GEMM for this 16-row tile ----
        int quad = lane >> 4, c = lane & 15;
        int m0 = blockIdx.x * 16;
        floatx4 acc0 = {0.f, 0.f, 0.f, 0.f};
        floatx4 acc1 = acc0, acc2 = acc0, acc3 = acc0;
#pragma unroll
        for (int kc = 0; kc < 64; kc += 32) {
            int ka = kc + quad * 8;
            short8 a = *(const short8*)(x1t + c * XST + ka);
            short8 b0 = *(const short8*)(Wt2 + (size_t)(c)      * 64 + ka);
            short8 b1 = *(const short8*)(Wt2 + (size_t)(16 + c) * 64 + ka);
            short8 b2 = *(const short8*)(Wt2 + (size_t)(32 + c) * 64 + ka);
            short8 b3 = *(const short8*)(Wt2 + (size_t)(48 + c) * 64 + ka);
            acc0 = __builtin_amdgcn_mfma_f32_16x16x32_bf16(a, b0, acc0, 0, 0, 0);
            acc1 = __builtin_amdgcn_mfma_f32_16x16x32_bf16(a, b1, acc1, 0, 0, 0);
            acc2 = __builtin_amdgcn_mfma_f32_16x16x32_bf16(a, b2, acc2, 0, 0, 0);
            acc3 = __builtin_amdgcn_mfma_f32_16x16x32_bf16(a, b3, acc3, 0, 0, 0);
        }
        float as0 = att_s2[c],      as1 = att_s2[16 + c], as2 = att_s2[32 + c], as3 = att_s2[48 + c];
        float ad0 = att_d2[c],      ad1 = att_d2[16 + c], ad2 = att_d2[32 + c], ad3 = att_d2[48 + c];
#pragma unroll
        for (int reg = 0; reg < 4; ++reg) {
            int row = m0 + quad * 4 + reg;
            float vs = acc0[reg] * as0 + acc1[reg] * as1 + acc2[reg] * as2 + acc3[reg] * as3;
            float vd = acc0[reg] * ad0 + acc1[reg] * ad1 + acc2[reg] * ad2 + acc3[reg] * ad3;
#pragma unroll
            for (int off = 1; off < 16; off <<= 1) {
                vs += __shfl_xor(vs, off);
                vd += __shfl_xor(vd, off);
            }
            if (row < N) {
                if (c == 0) { a_s2[row] = vs; a_d2[row] = vd; }
                unsigned short* hr = h2 + (size_t)row * F_OUT + c;
                hr[0]  = f2bf_bits(acc0[reg]);
                hr[16] = f2bf_bits(acc1[reg]);
                hr[32] = f2bf_bits(acc2[reg]);
                hr[48] = f2bf_bits(acc3[reg]);
            }
        }
    }
}

// ---------- D5a/D5b: layer-2 gather (phase P -> output cols P*32..P*32+31) ----------
__global__ void __launch_bounds__(256)
node_gather_half(const int* __restrict__ row_ptr, const int* __restrict__ eidx,
                 const float* __restrict__ a_s, const float* __restrict__ a_d,
                 const unsigned short* __restrict__ h, const float* __restrict__ bias,
                 void* __restrict__ out, int N, const int* __restrict__ flags, int phase) {
    int lane = threadIdx.x & 63;
    int wv = threadIdx.x >> 6;            // 0..3
    int ia = blockIdx.x * 8 + (wv << 1);
    int ib = ia + 1;
    if (ia >= N) return;
    int grp = lane >> 3, c8 = lane & 7;
    float sea, seb, acca[4], accb[4];
    gather_half8x2(ia, ib, grp, c8, phase, row_ptr, eidx, a_s, a_d, h,
                   &sea, acca, &seb, accb, N);
    if (grp == 0) {
        int col = (phase << 5) + (c8 << 2);
        int obf = flags[0];
#pragma unroll
        for (int nn = 0; nn < 2; ++nn) {
            int i = nn ? ib : ia;
            if (i >= N) break;
            float se = nn ? seb : sea;
            const float* ac = nn ? accb : acca;
            float inv = 1.f / (se + SOFT_EPS);
            float v[4];
#pragma unroll
            for (int k = 0; k < 4; ++k) v[k] = ac[k] * inv + bias[col + k];
            size_t o = (size_t)i * F_OUT + col;
            if (obf) {
                ushort4v ov;
#pragma unroll
                for (int k = 0; k < 4; ++k) ov[k] = f2bf_bits(v[k]);
                *(ushort4v*)((unsigned short*)out + o) = ov;
            } else {
                floatx4 o0 = {v[0], v[1], v[2], v[3]};
                *(floatx4*)((float*)out + o) = o0;
            }
        }
    }
}

extern "C" void kernel_launch(void* const* d_in, const int* in_sizes, int n_in,
                              void* d_out, int out_size, void* d_ws, size_t ws_size,
                              hipStream_t stream) {
    const void* x   = d_in[0];
    const void* ei  = d_in[1];
    const void* W1  = d_in[2];
    const void* as1 = d_in[3];
    const void* ad1 = d_in[4];
    const void* b1  = d_in[5];
    const void* W2  = d_in[6];
    const void* as2 = d_in[7];
    const void* ad2 = d_in[8];
    const void* b2  = d_in[9];

    int E  = in_sizes[1] / 2;          // 800000
    int n1 = in_sizes[2];              // 128*64
    int n2 = in_sizes[6];              // 64*64
    int K1 = n1 / F_OUT;               // 128
    int N  = in_sizes[0] / K1;         // 50000
    int total = E + N;
    int NB = (N + BW - 1) / BW;        // 196 buckets (<= TH)
    int nchunks = (total + CH - 1) / CH; // 104 chunks
    int M = NB * nchunks;              // raw count table size

    size_t nf = (size_t)N * F_OUT;
    char* wsb = (char*)d_ws;
    unsigned short* h   = (unsigned short*)wsb;                 // nf bf16 (layer-1)
    unsigned short* h2  = h + nf;                               // nf bf16 (layer-2)
    unsigned short* wt1 = h2 + nf;                              // n1 bf16
    unsigned short* wt2 = wt1 + n1;                             // n2 bf16
    float* a_s  = (float*)(wt2 + n2 + ((n1 + n2) & 1));         // N f32
    float* a_d  = a_s + N;
    float* a_s2 = a_d + N;
    float* a_d2 = a_s2 + N;
    float* vecs = a_d2 + N;                                     // 384 f32
    float* cAs1 = vecs,       *cAd1 = vecs + 64,  *cB1 = vecs + 128;
    float* cAs2 = vecs + 192, *cAd2 = vecs + 256, *cB2 = vecs + 320;
    int* flags    = (int*)(vecs + 384);
    int* row_ptr  = flags + 8;            // N+1
    int* eidx     = row_ptr + N + 1;      // total
    unsigned* staged = (unsigned*)(eidx + total); // total
    int* table    = (int*)(staged + total);       // M
    int* segbeg   = table + M;                    // NB+1
    char* xp = (char*)(segbeg + NB + 1);
    xp = (char*)(((size_t)xp + 15) & ~(size_t)15);
    unsigned short* x1lo = (unsigned short*)xp;   // N*32 bf16 (x1 lower half)

    int blkG1 = (N + 127) / 128;       // 391: 8 waves x 16 rows per block
    int blkP0 = (N + 7) / 8;           // 6250: 4 waves x 2 nodes per block
    int blkP1 = (N + 15) / 16;         // 3125: 8 waves x 2 nodes per block

    // D1: bucket histogram ∥ weight prep
    count_prep<<<nchunks + 1, TH, 0, stream>>>(ei, table, W1, as1, ad1, b1,
                                               W2, as2, ad2, b2, wt1, wt2, vecs, flags,
                                               E, total, NB, nchunks, n1, n2, K1);
    // D2: scatter (self-computed cursors) ∥ layer-1 GEMM
    scatter_gemm1<<<nchunks + blkG1, TH, 0, stream>>>(ei, table, staged, segbeg, row_ptr,
                                                      x, wt1, cAs1, cAd1, h, a_s, a_d,
                                                      (const unsigned*)W1,
                                                      E, total, NB, nchunks, N);
    // D3: per-bucket CSR
    bucket_csr<<<NB, TH3, 0, stream>>>(staged, segbeg, row_ptr, eidx, N);
    // D4a: layer-1 gather, cols 0..31 (3.2MB working set -> XCD-L2 resident)
    gather1_p0<<<blkP0, 256, 0, stream>>>(row_ptr, eidx, a_s, a_d, h, cB1, x1lo, N);
    // D4b: layer-1 gather, cols 32..63 + layer-2 GEMM
    gather1_p1<<<blkP1, 512, 0, stream>>>(row_ptr, eidx, a_s, a_d, h, cB1, x1lo,
                                          wt2, cAs2, cAd2, h2, a_s2, a_d2, N);
    // D5a/D5b: layer-2 gather halves -> output
    node_gather_half<<<blkP0, 256, 0, stream>>>(row_ptr, eidx, a_s2, a_d2, h2, cB2,
                                                d_out, N, flags, 0);
    node_gather_half<<<blkP0, 256, 0, stream>>>(row_ptr, eidx, a_s2, a_d2, h2, cB2,
                                                d_out, N, flags, 1);
}

// Round 11
// 178.754 us; speedup vs baseline: 1.1665x; 1.1665x over previous
//
#include <hip/hip_runtime.h>
#include <hip/hip_bf16.h>

#define F_OUT 64
#define NEG_SLOPE 0.2f
#define SOFT_EPS 1e-16f
#define BW 256          // nodes per bucket (i_local fits in 8 bits)
#define CH 8192         // edges per chunk
#define TH 512          // threads for count/scatter blocks
#define TH3 512         // threads for bucket_csr

typedef short short8 __attribute__((ext_vector_type(8)));
typedef float floatx4 __attribute__((ext_vector_type(4)));
typedef unsigned short ushort8v __attribute__((ext_vector_type(8)));
typedef long long ll2 __attribute__((ext_vector_type(2)));
typedef int int2v __attribute__((ext_vector_type(2)));

__device__ __forceinline__ unsigned short f2bf_bits(float v) {
    __hip_bfloat16 hb = __float2bfloat16(v);
    return *(unsigned short*)&hb;
}
__device__ __forceinline__ float bf_bits2f(unsigned short u) {
    __hip_bfloat16 hb = *(__hip_bfloat16*)&u;
    return __bfloat162float(hb);
}
__device__ __forceinline__ float read_any(const void* src, int off, int bf) {
    return bf ? __bfloat162float(((const __hip_bfloat16*)src)[off])
              : ((const float*)src)[off];
}
__device__ __forceinline__ int get_idx(const void* ei, int i64, long long pos) {
    return i64 ? (int)((const long long*)ei)[pos] : ((const int*)ei)[pos];
}

// Per-block dtype detection (64-lane ballot on W1 low-halves / ei high words).
__device__ __forceinline__ void detect_local(const unsigned* wbits, const unsigned* ebits,
                                             int* sm_bf, int* sm_i64) {
    if (threadIdx.x < 64) {
        unsigned w = wbits[threadIdx.x];
        unsigned e = (w >> 7) & 0xFFu;
        unsigned long long mb = __ballot(e >= 0x60u && e <= 0x7Eu);
        unsigned long long mz = __ballot(ebits[2 * threadIdx.x + 1] == 0u);
        if (threadIdx.x == 0) { *sm_bf = (__popcll(mb) > 32); *sm_i64 = (__popcll(mz) > 32); }
    }
    __syncthreads();
}

// Load a pair of indices (stream base + t, t+1) vectorized.
__device__ __forceinline__ void load_idx2(const void* ei, int i64, long long base, int t,
                                          int* v0, int* v1) {
    if (i64) {
        ll2 d = *(const ll2*)((const long long*)ei + base + t);
        *v0 = (int)d[0]; *v1 = (int)d[1];
    } else {
        int2v d = *(const int2v*)((const int*)ei + base + t);
        *v0 = d[0]; *v1 = d[1];
    }
}

// ---------- D1: bucket_count (blocks 0..nchunks-1) ∥ prep weights (block nchunks) ----------
__global__ void count_prep(const void* __restrict__ ei, int* __restrict__ table,
                           const void* w1, const void* as1, const void* ad1, const void* b1,
                           const void* w2, const void* as2, const void* ad2, const void* b2,
                           unsigned short* __restrict__ wt1, unsigned short* __restrict__ wt2,
                           float* __restrict__ vecs, int* __restrict__ flags,
                           int E, int total, int NB, int nchunks, int n1, int n2, int K1) {
    __shared__ int cnt[1024];
    __shared__ int s_bf, s_i64;
    detect_local((const unsigned*)w1, (const unsigned*)ei, &s_bf, &s_i64);
    int bf = s_bf, i64 = s_i64;
    int g = blockIdx.x, tid = threadIdx.x;
    if (g == 0 && tid == 0) { flags[0] = bf; flags[1] = i64; }

    if (g < nchunks) {                     // ---- counting block ----
        for (int k = tid; k < NB; k += TH) cnt[k] = 0;
        __syncthreads();
        int base = g * CH;
        int lim = base + CH < total ? base + CH : total;
        int elim = lim < E ? lim : E;      // edge sub-range end
        for (int t = base + tid * 2; t < elim; t += TH * 2) {
            if (t + 1 < elim) {
                int i0, i1;
                load_idx2(ei, i64, (long long)E, t, &i0, &i1);
                atomicAdd(&cnt[i0 >> 8], 1);
                atomicAdd(&cnt[i1 >> 8], 1);
            } else {
                int i0 = get_idx(ei, i64, (long long)E + t);
                atomicAdd(&cnt[i0 >> 8], 1);
            }
        }
        for (int t = (base > E ? base : E) + tid; t < lim; t += TH)
            atomicAdd(&cnt[(t - E) >> 8], 1);
        __syncthreads();
        for (int k = tid; k < NB; k += TH) table[k * nchunks + g] = cnt[k];
    } else {                               // ---- weight-prep block ----
        int wtotal = n1 + n2 + 384;
        for (int t = tid; t < wtotal; t += TH) {
            if (t < n1) {
                int n = t / K1, k = t - n * K1;
                wt1[t] = f2bf_bits(read_any(w1, k * F_OUT + n, bf));
            } else if (t < n1 + n2) {
                int u = t - n1;
                int n = u >> 6, k = u & 63;
                wt2[u] = f2bf_bits(read_any(w2, k * F_OUT + n, bf));
            } else {
                int u = t - n1 - n2;
                const void* srcp[6] = {as1, ad1, b1, as2, ad2, b2};
                vecs[u] = read_any(srcp[u >> 6], u & 63, bf);
            }
        }
    }
}

// ---------- MFMA GEMM body (WAVES waves x 16 rows per block, global bf16/f32 A) ----------
template <int K, int WAVES>
__device__ __forceinline__ void gemm_body(int blk, int tid,
                          const void* __restrict__ xv, const unsigned short* __restrict__ Wt,
                          const float* __restrict__ att_s, const float* __restrict__ att_d,
                          unsigned short* __restrict__ h, float* __restrict__ a_s,
                          float* __restrict__ a_d, int N, int bf) {
    int lane = tid & 63;
    int m0 = (blk * WAVES + (tid >> 6)) * 16;
    if (m0 >= N) return;
    int c = lane & 15, quad = lane >> 4;
    int arow = m0 + c;
    if (arow >= N) arow = N - 1;

    floatx4 acc0 = {0.f, 0.f, 0.f, 0.f};
    floatx4 acc1 = acc0, acc2 = acc0, acc3 = acc0;

    for (int kc = 0; kc < K; kc += 32) {
        int ka = kc + quad * 8;
        short8 a;
        if (bf) {
            a = *(const short8*)((const unsigned short*)xv + (size_t)arow * K + ka);
        } else {
            const float* xp = (const float*)xv + (size_t)arow * K + ka;
            floatx4 f0 = *(const floatx4*)xp;
            floatx4 f1 = *(const floatx4*)(xp + 4);
#pragma unroll
            for (int j = 0; j < 4; ++j) {
                a[j]     = (short)f2bf_bits(f0[j]);
                a[4 + j] = (short)f2bf_bits(f1[j]);
            }
        }
        short8 b0 = *(const short8*)(Wt + (size_t)(c)      * K + ka);
        short8 b1 = *(const short8*)(Wt + (size_t)(16 + c) * K + ka);
        short8 b2 = *(const short8*)(Wt + (size_t)(32 + c) * K + ka);
        short8 b3 = *(const short8*)(Wt + (size_t)(48 + c) * K + ka);
        acc0 = __builtin_amdgcn_mfma_f32_16x16x32_bf16(a, b0, acc0, 0, 0, 0);
        acc1 = __builtin_amdgcn_mfma_f32_16x16x32_bf16(a, b1, acc1, 0, 0, 0);
        acc2 = __builtin_amdgcn_mfma_f32_16x16x32_bf16(a, b2, acc2, 0, 0, 0);
        acc3 = __builtin_amdgcn_mfma_f32_16x16x32_bf16(a, b3, acc3, 0, 0, 0);
    }

    float as0 = att_s[c],      as1 = att_s[16 + c], as2 = att_s[32 + c], as3 = att_s[48 + c];
    float ad0 = att_d[c],      ad1 = att_d[16 + c], ad2 = att_d[32 + c], ad3 = att_d[48 + c];
#pragma unroll
    for (int reg = 0; reg < 4; ++reg) {
        int row = m0 + quad * 4 + reg;
        float vs = acc0[reg] * as0 + acc1[reg] * as1 + acc2[reg] * as2 + acc3[reg] * as3;
        float vd = acc0[reg] * ad0 + acc1[reg] * ad1 + acc2[reg] * ad2 + acc3[reg] * ad3;
#pragma unroll
        for (int off = 1; off < 16; off <<= 1) {
            vs += __shfl_xor(vs, off);
            vd += __shfl_xor(vd, off);
        }
        if (row < N) {
            if (c == 0) { a_s[row] = vs; a_d[row] = vd; }
            unsigned short* hr = h + (size_t)row * F_OUT + c;
            hr[0]  = f2bf_bits(acc0[reg]);
            hr[16] = f2bf_bits(acc1[reg]);
            hr[32] = f2bf_bits(acc2[reg]);
            hr[48] = f2bf_bits(acc3[reg]);
        }
    }
}

// ---------- D2: scatter (blocks < nchunks, cursors self-computed from raw table)
//              ∥ layer-1 GEMM (remaining blocks, 8 waves x 16 rows) ----------
__global__ void __launch_bounds__(TH)
scatter_gemm1(const void* __restrict__ ei, const int* __restrict__ table,
              unsigned* __restrict__ staged, int* __restrict__ segbeg,
              int* __restrict__ row_ptr, const void* __restrict__ xv,
              const unsigned short* __restrict__ Wt,
              const float* __restrict__ att_s, const float* __restrict__ att_d,
              unsigned short* __restrict__ h, float* __restrict__ a_s,
              float* __restrict__ a_d, const unsigned* __restrict__ wbits,
              int E, int total, int NB, int nchunks, int N) {
    __shared__ int s_bf, s_i64;
    detect_local(wbits, (const unsigned*)ei, &s_bf, &s_i64);
    int tid = threadIdx.x;
    if ((int)blockIdx.x >= nchunks) {      // ---- layer-1 GEMM role ----
        gemm_body<128, 8>(blockIdx.x - nchunks, tid, xv, Wt, att_s, att_d,
                          h, a_s, a_d, N, s_bf);
        return;
    }
    // ---- scatter role ----
    __shared__ int s_scan[TH];
    __shared__ int s_cur[1024];
    int g = blockIdx.x;
    int i64 = s_i64;
    int b0 = 0;
    if (tid < NB) {                        // NB (=196) <= TH
        const int* row = table + (size_t)tid * nchunks;
        int rsum = 0, rpart = 0;
        for (int c2 = 0; c2 < nchunks; ++c2) {
            int v = row[c2];
            rsum += v;
            rpart += (c2 < g) ? v : 0;
        }
        b0 = rsum;
        s_cur[tid] = rpart;
    }
    s_scan[tid] = (tid < NB) ? b0 : 0;
    __syncthreads();
    for (int off = 1; off < TH; off <<= 1) {   // Hillis-Steele inclusive scan
        int v = (tid >= off) ? s_scan[tid - off] : 0;
        __syncthreads();
        s_scan[tid] += v;
        __syncthreads();
    }
    if (tid < NB) {
        int excl = s_scan[tid] - b0;
        s_cur[tid] = excl + s_cur[tid];
        if (g == 0) segbeg[tid] = excl;
    }
    if (g == 0 && tid == 0) { segbeg[NB] = total; row_ptr[N] = total; }
    __syncthreads();
    int base = g * CH;
    int lim = base + CH < total ? base + CH : total;
    int elim = lim < E ? lim : E;          // edge sub-range end
    for (int t = base + tid * 2; t < elim; t += TH * 2) {
        if (t + 1 < elim) {
            int j0, j1, i0, i1;
            load_idx2(ei, i64, 0, t, &j0, &j1);
            load_idx2(ei, i64, (long long)E, t, &i0, &i1);
            int pos0 = atomicAdd(&s_cur[i0 >> 8], 1);
            staged[pos0] = ((unsigned)(i0 & 255) << 24) | (unsigned)j0;
            int pos1 = atomicAdd(&s_cur[i1 >> 8], 1);
            staged[pos1] = ((unsigned)(i1 & 255) << 24) | (unsigned)j1;
        } else {
            int j0 = get_idx(ei, i64, t);
            int i0 = get_idx(ei, i64, (long long)E + t);
            int pos0 = atomicAdd(&s_cur[i0 >> 8], 1);
            staged[pos0] = ((unsigned)(i0 & 255) << 24) | (unsigned)j0;
        }
    }
    for (int t = (base > E ? base : E) + tid; t < lim; t += TH) {
        int v = t - E;
        int pos = atomicAdd(&s_cur[v >> 8], 1);
        staged[pos] = ((unsigned)(v & 255) << 24) | (unsigned)v;
    }
}

// ---------- D3: per-bucket CSR (row_ptr + in-segment eidx) ----------
__global__ void __launch_bounds__(TH3)
bucket_csr(const unsigned* __restrict__ staged, const int* __restrict__ segbeg,
           int* __restrict__ row_ptr, int* __restrict__ eidx, int N) {
    __shared__ int ldeg[BW];
    __shared__ int lcur[BW];
    __shared__ int wtot[4];
    int b = blockIdx.x;
    int t = threadIdx.x;
    int seg_beg = segbeg[b];
    int seg_end = segbeg[b + 1];
    if (t < BW) ldeg[t] = 0;
    __syncthreads();
    for (int p = seg_beg + t; p < seg_end; p += TH3)
        atomicAdd(&ldeg[staged[p] >> 24], 1);
    __syncthreads();
    int lane = t & 63, w = t >> 6;
    int d = 0, v = 0;
    if (t < BW) {
        d = ldeg[t];
        v = d;
#pragma unroll
        for (int off = 1; off < 64; off <<= 1) {
            int u = __shfl_up(v, off);
            if (lane >= off) v += u;
        }
        if (lane == 63) wtot[w] = v;
    }
    __syncthreads();
    if (t < BW) {
        int woff = 0;
        for (int k = 0; k < w; ++k) woff += wtot[k];
        int excl = v - d + woff;
        int node = b * BW + t;
        if (node < N) row_ptr[node] = seg_beg + excl;
        lcur[t] = excl;
    }
    __syncthreads();
    for (int p = seg_beg + t; p < seg_end; p += TH3) {
        unsigned pk = staged[p];
        int pos = atomicAdd(&lcur[pk >> 24], 1);
        eidx[seg_beg + pos] = (int)(pk & 0xFFFFFFu);
    }
}

// ---------- dual-node gather wave body ----------
// 8 groups of 8 lanes; each group owns 1/8 of BOTH nodes' edge lists and the
// loop interleaves them: one wave-level h-load instruction covers 8 distinct
// rows (one per group), so the 2-wide x 2-stream body keeps ~32 rows in
// flight per wave. Exhausted streams issue dummy j=0 loads with w=0 (L1-hot,
// harmless). Epilogue: one 3-level xor(8/16/32) butterfly per node.
__device__ __forceinline__ void gather_node8x2(int ia, int ib, int grp, int c8,
                                               const int* __restrict__ row_ptr,
                                               const int* __restrict__ eidx,
                                               const float* __restrict__ a_s,
                                               const float* __restrict__ a_d,
                                               const unsigned short* __restrict__ h,
                                               float* sea_out, float acca[8],
                                               float* seb_out, float accb[8], int N) {
    const char* hb8 = (const char*)h;
    unsigned cofs = (unsigned)(c8 << 4);
    int bega = row_ptr[ia], enda = row_ptr[ia + 1];
    int lena = enda - bega;
    float ada = a_d[ia];
    int pa = bega + ((lena * grp) >> 3);
    int gea = bega + ((lena * (grp + 1)) >> 3);
    int pb = 0, geb = 0;
    float adb = 0.f;
    if (ib < N) {
        int begb = row_ptr[ib], endb = row_ptr[ib + 1];
        int lenb = endb - begb;
        adb = a_d[ib];
        pb = begb + ((lenb * grp) >> 3);
        geb = begb + ((lenb * (grp + 1)) >> 3);
    }
    float sea = 0.f, seb = 0.f;
#pragma unroll
    for (int k = 0; k < 8; ++k) { acca[k] = 0.f; accb[k] = 0.f; }

    while (pa < gea || pb < geb) {
        bool va0 = pa < gea, va1 = pa + 1 < gea;
        bool vb0 = pb < geb, vb1 = pb + 1 < geb;
        int ja0 = va0 ? eidx[pa]     : 0;
        int ja1 = va1 ? eidx[pa + 1] : 0;
        int jb0 = vb0 ? eidx[pb]     : 0;
        int jb1 = vb1 ? eidx[pb + 1] : 0;
        ushort8v ha0 = *(const ushort8v*)(hb8 + (((unsigned)ja0 << 7) + cofs));
        ushort8v ha1 = *(const ushort8v*)(hb8 + (((unsigned)ja1 << 7) + cofs));
        ushort8v hb0 = *(const ushort8v*)(hb8 + (((unsigned)jb0 << 7) + cofs));
        ushort8v hb1 = *(const ushort8v*)(hb8 + (((unsigned)jb1 << 7) + cofs));
        float ea0 = a_s[ja0] + ada;
        float ea1 = a_s[ja1] + ada;
        float eb0 = a_s[jb0] + adb;
        float eb1 = a_s[jb1] + adb;
        float wa0 = va0 ? __expf(fmaxf(ea0, NEG_SLOPE * ea0)) : 0.f;
        float wa1 = va1 ? __expf(fmaxf(ea1, NEG_SLOPE * ea1)) : 0.f;
        float wb0 = vb0 ? __expf(fmaxf(eb0, NEG_SLOPE * eb0)) : 0.f;
        float wb1 = vb1 ? __expf(fmaxf(eb1, NEG_SLOPE * eb1)) : 0.f;
        sea += wa0 + wa1;
        seb += wb0 + wb1;
#pragma unroll
        for (int k = 0; k < 8; ++k) {
            acca[k] += wa0 * bf_bits2f(ha0[k]) + wa1 * bf_bits2f(ha1[k]);
            accb[k] += wb0 * bf_bits2f(hb0[k]) + wb1 * bf_bits2f(hb1[k]);
        }
        pa += 2; pb += 2;
    }

    // cross-group reduce: 3 levels, every lane ends with full sums
#pragma unroll
    for (int off = 8; off < 64; off <<= 1) {
        sea += __shfl_xor(sea, off);
        seb += __shfl_xor(seb, off);
#pragma unroll
        for (int k = 0; k < 8; ++k) {
            acca[k] += __shfl_xor(acca[k], off);
            accb[k] += __shfl_xor(accb[k], off);
        }
    }
    *sea_out = sea;
    *seb_out = seb;
}

// ---------- D4: layer-1 gather (8 waves x 2 nodes = 16 rows) + layer-2 GEMM ----------
#define XST 72
__global__ void __launch_bounds__(512)
gather1_gemm2(const int* __restrict__ row_ptr, const int* __restrict__ eidx,
              const float* __restrict__ a_s, const float* __restrict__ a_d,
              const unsigned short* __restrict__ h, const float* __restrict__ bias,
              const unsigned short* __restrict__ Wt2,
              const float* __restrict__ att_s2, const float* __restrict__ att_d2,
              unsigned short* __restrict__ h2, float* __restrict__ a_s2,
              float* __restrict__ a_d2, int N) {
    __shared__ unsigned short x1t[16 * XST];
    int tid = threadIdx.x;
    int lane = tid & 63;
    int wv = tid >> 6;                    // 0..7 -> rows 2wv, 2wv+1
    int grp = lane >> 3, c8 = lane & 7;
    int ia = blockIdx.x * 16 + (wv << 1);
    int ib = ia + 1;

    if (ia < N) {
        float sea, seb, acca[8], accb[8];
        gather_node8x2(ia, ib, grp, c8, row_ptr, eidx, a_s, a_d, h,
                       &sea, acca, &seb, accb, N);
        if (grp == 0) {
            int col = c8 << 3;
            float inv = 1.f / (sea + SOFT_EPS);
            ushort8v ov;
#pragma unroll
            for (int k = 0; k < 8; ++k) {
                float v = acca[k] * inv + bias[col + k];
                ov[k] = f2bf_bits(v > 0.f ? v : 0.f);
            }
            *(ushort8v*)(x1t + (wv * 2) * XST + col) = ov;
            if (ib < N) {
                inv = 1.f / (seb + SOFT_EPS);
#pragma unroll
                for (int k = 0; k < 8; ++k) {
                    float v = accb[k] * inv + bias[col + k];
                    ov[k] = f2bf_bits(v > 0.f ? v : 0.f);
                }
            } else {
                ov = (ushort8v){0, 0, 0, 0, 0, 0, 0, 0};
            }
            *(ushort8v*)(x1t + (wv * 2 + 1) * XST + col) = ov;
        }
    } else if (grp == 0) {
        *(ushort8v*)(x1t + (wv * 2)     * XST + (c8 << 3)) = (ushort8v){0, 0, 0, 0, 0, 0, 0, 0};
        *(ushort8v*)(x1t + (wv * 2 + 1) * XST + (c8 << 3)) = (ushort8v){0, 0, 0, 0, 0, 0, 0, 0};
    }
    __syncthreads();

    if (wv == 0) {                        // ---- layer-2 GEMM for this 16-row tile ----
        int quad = lane >> 4, c = lane & 15;
        int m0 = blockIdx.x * 16;
        floatx4 acc0 = {0.f, 0.f, 0.f, 0.f};
        floatx4 acc1 = acc0, acc2 = acc0, acc3 = acc0;
#pragma unroll
        for (int kc = 0; kc < 64; kc += 32) {
            int ka = kc + quad * 8;
            short8 a = *(const short8*)(x1t + c * XST + ka);
            short8 b0 = *(const short8*)(Wt2 + (size_t)(c)      * 64 + ka);
            short8 b1 = *(const short8*)(Wt2 + (size_t)(16 + c) * 64 + ka);
            short8 b2 = *(const short8*)(Wt2 + (size_t)(32 + c) * 64 + ka);
            short8 b3 = *(const short8*)(Wt2 + (size_t)(48 + c) * 64 + ka);
            acc0 = __builtin_amdgcn_mfma_f32_16x16x32_bf16(a, b0, acc0, 0, 0, 0);
            acc1 = __builtin_amdgcn_mfma_f32_16x16x32_bf16(a, b1, acc1, 0, 0, 0);
            acc2 = __builtin_amdgcn_mfma_f32_16x16x32_bf16(a, b2, acc2, 0, 0, 0);
            acc3 = __builtin_amdgcn_mfma_f32_16x16x32_bf16(a, b3, acc3, 0, 0, 0);
        }
        float as0 = att_s2[c],      as1 = att_s2[16 + c], as2 = att_s2[32 + c], as3 = att_s2[48 + c];
        float ad0 = att_d2[c],      ad1 = att_d2[16 + c], ad2 = att_d2[32 + c], ad3 = att_d2[48 + c];
#pragma unroll
        for (int reg = 0; reg < 4; ++reg) {
            int row = m0 + quad * 4 + reg;
            float vs = acc0[reg] * as0 + acc1[reg] * as1 + acc2[reg] * as2 + acc3[reg] * as3;
            float vd = acc0[reg] * ad0 + acc1[reg] * ad1 + acc2[reg] * ad2 + acc3[reg] * ad3;
#pragma unroll
            for (int off = 1; off < 16; off <<= 1) {
                vs += __shfl_xor(vs, off);
                vd += __shfl_xor(vd, off);
            }
            if (row < N) {
                if (c == 0) { a_s2[row] = vs; a_d2[row] = vd; }
                unsigned short* hr = h2 + (size_t)row * F_OUT + c;
                hr[0]  = f2bf_bits(acc0[reg]);
                hr[16] = f2bf_bits(acc1[reg]);
                hr[32] = f2bf_bits(acc2[reg]);
                hr[48] = f2bf_bits(acc3[reg]);
            }
        }
    }
}

// ---------- D5: layer-2 gather (4 waves x 2 nodes) -> final output ----------
__global__ void __launch_bounds__(256)
node_gather_out(const int* __restrict__ row_ptr, const int* __restrict__ eidx,
                const float* __restrict__ a_s, const float* __restrict__ a_d,
                const unsigned short* __restrict__ h, const float* __restrict__ bias,
                void* __restrict__ out, int N, const int* __restrict__ flags) {
    int lane = threadIdx.x & 63;
    int wv = threadIdx.x >> 6;            // 0..3
    int ia = blockIdx.x * 8 + (wv << 1);
    int ib = ia + 1;
    if (ia >= N) return;
    int grp = lane >> 3, c8 = lane & 7;
    float sea, seb, acca[8], accb[8];
    gather_node8x2(ia, ib, grp, c8, row_ptr, eidx, a_s, a_d, h,
                   &sea, acca, &seb, accb, N);
    if (grp == 0) {
        int col = c8 << 3;
        int obf = flags[0];
#pragma unroll
        for (int nn = 0; nn < 2; ++nn) {
            int i = nn ? ib : ia;
            if (i >= N) break;
            float se = nn ? seb : sea;
            const float* ac = nn ? accb : acca;
            float inv = 1.f / (se + SOFT_EPS);
            float v[8];
#pragma unroll
            for (int k = 0; k < 8; ++k) v[k] = ac[k] * inv + bias[col + k];
            size_t o = (size_t)i * F_OUT + col;
            if (obf) {
                ushort8v ov;
#pragma unroll
                for (int k = 0; k < 8; ++k) ov[k] = f2bf_bits(v[k]);
                *(ushort8v*)((unsigned short*)out + o) = ov;
            } else {
                floatx4 o0 = {v[0], v[1], v[2], v[3]};
                floatx4 o1 = {v[4], v[5], v[6], v[7]};
                *(floatx4*)((float*)out + o) = o0;
                *(floatx4*)((float*)out + o + 4) = o1;
            }
        }
    }
}

extern "C" void kernel_launch(void* const* d_in, const int* in_sizes, int n_in,
                              void* d_out, int out_size, void* d_ws, size_t ws_size,
                              hipStream_t stream) {
    const void* x   = d_in[0];
    const void* ei  = d_in[1];
    const void* W1  = d_in[2];
    const void* as1 = d_in[3];
    const void* ad1 = d_in[4];
    const void* b1  = d_in[5];
    const void* W2  = d_in[6];
    const void* as2 = d_in[7];
    const void* ad2 = d_in[8];
    const void* b2  = d_in[9];

    int E  = in_sizes[1] / 2;          // 800000
    int n1 = in_sizes[2];              // 128*64
    int n2 = in_sizes[6];              // 64*64
    int K1 = n1 / F_OUT;               // 128
    int N  = in_sizes[0] / K1;         // 50000
    int total = E + N;
    int NB = (N + BW - 1) / BW;        // 196 buckets (<= TH)
    int nchunks = (total + CH - 1) / CH; // 104 chunks
    int M = NB * nchunks;              // raw count table size

    size_t nf = (size_t)N * F_OUT;
    char* wsb = (char*)d_ws;
    unsigned short* h   = (unsigned short*)wsb;                 // nf bf16 (layer-1)
    unsigned short* h2  = h + nf;                               // nf bf16 (layer-2)
    unsigned short* wt1 = h2 + nf;                              // n1 bf16
    unsigned short* wt2 = wt1 + n1;                             // n2 bf16
    float* a_s  = (float*)(wt2 + n2 + ((n1 + n2) & 1));         // N f32
    float* a_d  = a_s + N;
    float* a_s2 = a_d + N;
    float* a_d2 = a_s2 + N;
    float* vecs = a_d2 + N;                                     // 384 f32
    float* cAs1 = vecs,       *cAd1 = vecs + 64,  *cB1 = vecs + 128;
    float* cAs2 = vecs + 192, *cAd2 = vecs + 256, *cB2 = vecs + 320;
    int* flags    = (int*)(vecs + 384);
    int* row_ptr  = flags + 8;            // N+1
    int* eidx     = row_ptr + N + 1;      // total
    unsigned* staged = (unsigned*)(eidx + total); // total
    int* table    = (int*)(staged + total);       // M
    int* segbeg   = table + M;                    // NB+1

    int blkG1 = (N + 127) / 128;       // 391: 8 waves x 16 rows per block
    int blkFuse = (N + 15) / 16;       // 3125: 8 waves x 2 nodes per block
    int blkNode = (N + 7) / 8;         // 6250: 4 waves x 2 nodes per block

    // D1: bucket histogram ∥ weight prep
    count_prep<<<nchunks + 1, TH, 0, stream>>>(ei, table, W1, as1, ad1, b1,
                                               W2, as2, ad2, b2, wt1, wt2, vecs, flags,
                                               E, total, NB, nchunks, n1, n2, K1);
    // D2: scatter (self-computed cursors) ∥ layer-1 GEMM
    scatter_gemm1<<<nchunks + blkG1, TH, 0, stream>>>(ei, table, staged, segbeg, row_ptr,
                                                      x, wt1, cAs1, cAd1, h, a_s, a_d,
                                                      (const unsigned*)W1,
                                                      E, total, NB, nchunks, N);
    // D3: per-bucket CSR
    bucket_csr<<<NB, TH3, 0, stream>>>(staged, segbeg, row_ptr, eidx, N);
    // D4: layer-1 gather (dual-node waves) fused with layer-2 GEMM
    gather1_gemm2<<<blkFuse, 512, 0, stream>>>(row_ptr, eidx, a_s, a_d, h, cB1,
                                               wt2, cAs2, cAd2, h2, a_s2, a_d2, N);
    // D5: layer-2 gather (dual-node waves) -> output
    node_gather_out<<<blkNode, 256, 0, stream>>>(row_ptr, eidx, a_s2, a_d2, h2, cB2,
                                                 d_out, N, flags);
}